// Round 9
// baseline (1673.080 us; speedup 1.0000x reference)
//
#include <hip/hip_runtime.h>

// AF-LSTM on MI355X. Sizes fixed: V=32000, D=H=512, B=64, T=256, A=4, 4H=2048.
// All float tensors f32; x,s int32; d_out f32 [64,512].
// R8: 1388us, recurrence 758us (2.96us/step) -- fence-free sentinel polling
// confirmed (was 5us/step with acquire/release L2-invalidate thrash).
// R9: (a) incremental staging: each dword stored to LDS on arrival, busy
// re-poll of pending only (no s_sleep quantization); (b) own-chunk bypass:
// gate threads write their h directly into next-step hsm, poll only 15/16
// chunks; (c) 4 independent MFMA accumulators (cut 16-deep dep chain);
// (d) G1 rewritten at 128x128 tile (4x4 frags/wave, m93-style).

typedef __bf16 bf16x8 __attribute__((ext_vector_type(8)));
typedef float f32x4 __attribute__((ext_vector_type(4)));

#define B_ 64
#define T_ 256
#define D_ 512
#define H4 2048

__device__ __forceinline__ unsigned short f2bf(float f) {
    unsigned u = __float_as_uint(f);
    u += 0x7fffu + ((u >> 16) & 1u);   // round-to-nearest-even
    return (unsigned short)(u >> 16);
}
__device__ __forceinline__ float bf2f(unsigned short x) {
    return __uint_as_float(((unsigned)x) << 16);
}
__device__ __forceinline__ float bf2f_lo(unsigned u) { return __uint_as_float(u << 16); }
__device__ __forceinline__ float bf2f_hi(unsigned u) { return __uint_as_float(u & 0xffff0000u); }
__device__ __forceinline__ float sigmoidf_(float x) {
    return 1.f / (1.f + expf(-x));
}

// ---------------------------------------------------------------------------
// Generic C = A @ B^T GEMM, 64x64 tile (used by G2/G3/G4; unchanged from R3).
// ---------------------------------------------------------------------------
__global__ __launch_bounds__(256)
void gemm_bt(const void* __restrict__ Abase, int a_f32,
             const int* __restrict__ gather_idx,
             const float* __restrict__ Bmat,
             const float* __restrict__ circ_src,
             const float* __restrict__ bias,
             unsigned short* __restrict__ outb,
             float* __restrict__ outf,
             int N, int K,
             long A_bstride, long out_bstride,
             int act)
{
    __shared__ __align__(16) unsigned short Asm[64 * 40];
    __shared__ __align__(16) unsigned short Bsm[64 * 40];

    const int bz = blockIdx.z;
    const int tile_n = blockIdx.x * 64;
    const int tile_m = blockIdx.y * 64;
    const int tid = threadIdx.x;
    const int lane = tid & 63;
    const int w = tid >> 6;
    const int wm = (w >> 1) * 32;
    const int wn = (w & 1) * 32;

    const int srow = tid >> 2;
    const int skc = (tid & 3) * 8;

    const float* arow_f = nullptr;
    const unsigned short* arow_h = nullptr;
    if (a_f32) {
        const float* Af = (const float*)Abase;
        if (gather_idx) arow_f = Af + (long)gather_idx[tile_m + srow] * K;
        else            arow_f = Af + (long)bz * A_bstride + (long)(tile_m + srow) * K;
    } else {
        arow_h = (const unsigned short*)Abase + (long)bz * A_bstride + (long)(tile_m + srow) * K;
    }
    const float* brow = nullptr;
    const float* csrc = nullptr;
    if (circ_src) csrc = circ_src + bz * 512;
    else brow = Bmat + (long)(tile_n + srow) * K;

    f32x4 zero4 = {0.f, 0.f, 0.f, 0.f};
    f32x4 acc00 = zero4, acc01 = zero4, acc10 = zero4, acc11 = zero4;

    const int fr = lane & 15;
    const int fq = (lane >> 4) * 8;

    for (int kc = 0; kc < K; kc += 32) {
        __syncthreads();
        if (a_f32) {
            float4 u0 = *(const float4*)(arow_f + kc + skc);
            float4 u1 = *(const float4*)(arow_f + kc + skc + 4);
            unsigned short tmp[8] __attribute__((aligned(16)));
            tmp[0] = f2bf(u0.x); tmp[1] = f2bf(u0.y); tmp[2] = f2bf(u0.z); tmp[3] = f2bf(u0.w);
            tmp[4] = f2bf(u1.x); tmp[5] = f2bf(u1.y); tmp[6] = f2bf(u1.z); tmp[7] = f2bf(u1.w);
            *(uint4*)&Asm[srow * 40 + skc] = *(const uint4*)tmp;
        } else {
            *(uint4*)&Asm[srow * 40 + skc] = *(const uint4*)(arow_h + kc + skc);
        }
        if (csrc) {
            unsigned short tmp[8] __attribute__((aligned(16)));
            int n_abs = tile_n + srow;
            #pragma unroll
            for (int j = 0; j < 8; j++) {
                int k_abs = kc + skc + j;
                tmp[j] = f2bf(csrc[(k_abs - n_abs) & 511]);
            }
            *(uint4*)&Bsm[srow * 40 + skc] = *(const uint4*)tmp;
        } else {
            float4 u0 = *(const float4*)(brow + kc + skc);
            float4 u1 = *(const float4*)(brow + kc + skc + 4);
            unsigned short tmp[8] __attribute__((aligned(16)));
            tmp[0] = f2bf(u0.x); tmp[1] = f2bf(u0.y); tmp[2] = f2bf(u0.z); tmp[3] = f2bf(u0.w);
            tmp[4] = f2bf(u1.x); tmp[5] = f2bf(u1.y); tmp[6] = f2bf(u1.z); tmp[7] = f2bf(u1.w);
            *(uint4*)&Bsm[srow * 40 + skc] = *(const uint4*)tmp;
        }
        __syncthreads();
        bf16x8 a0 = *(const bf16x8*)&Asm[(wm + fr) * 40 + fq];
        bf16x8 a1 = *(const bf16x8*)&Asm[(wm + 16 + fr) * 40 + fq];
        bf16x8 b0 = *(const bf16x8*)&Bsm[(wn + fr) * 40 + fq];
        bf16x8 b1 = *(const bf16x8*)&Bsm[(wn + 16 + fr) * 40 + fq];
        acc00 = __builtin_amdgcn_mfma_f32_16x16x32_bf16(a0, b0, acc00, 0, 0, 0);
        acc01 = __builtin_amdgcn_mfma_f32_16x16x32_bf16(a0, b1, acc01, 0, 0, 0);
        acc10 = __builtin_amdgcn_mfma_f32_16x16x32_bf16(a1, b0, acc10, 0, 0, 0);
        acc11 = __builtin_amdgcn_mfma_f32_16x16x32_bf16(a1, b1, acc11, 0, 0, 0);
    }

    #pragma unroll
    for (int mi = 0; mi < 2; mi++) {
        #pragma unroll
        for (int ni = 0; ni < 2; ni++) {
            f32x4 acc = (mi == 0) ? (ni == 0 ? acc00 : acc01)
                                  : (ni == 0 ? acc10 : acc11);
            #pragma unroll
            for (int rg = 0; rg < 4; rg++) {
                int row = tile_m + wm + mi * 16 + (lane >> 4) * 4 + rg;
                int col = tile_n + wn + ni * 16 + (lane & 15);
                float v = acc[rg];
                if (bias) v += bias[col];
                if (act == 1) v = tanhf(v);
                long oidx = (long)bz * out_bstride + (long)row * N + col;
                if (outb) outb[oidx] = f2bf(v);
                else outf[oidx] = v;
            }
        }
    }
}

// ---------------------------------------------------------------------------
// G1 at 128x128 tile: Zx = embed[x] @ W_ih^T + b_lstm.
// grid (16,128), block 256 (4 waves, 2x2; each wave 64x64 via 4x4 frags).
// A rows gathered from f32 embed; B rows from f32 W_ih; cvt during staging.
// ---------------------------------------------------------------------------
__global__ __launch_bounds__(256)
void gemm128_g1(const float* __restrict__ embed,
                const int* __restrict__ xidx,
                const float* __restrict__ Wih,
                const float* __restrict__ bias,
                unsigned short* __restrict__ Zx)
{
    __shared__ __align__(16) unsigned short Asm[128 * 40];
    __shared__ __align__(16) unsigned short Bsm[128 * 40];

    const int tile_n = blockIdx.x * 128;
    const int tile_m = blockIdx.y * 128;
    const int tid = threadIdx.x;
    const int lane = tid & 63;
    const int w = tid >> 6;
    const int wm = (w >> 1) * 64;
    const int wn = (w & 1) * 64;
    const int fr = lane & 15;
    const int fq = (lane >> 4) * 8;

    const int sr = tid >> 1;            // staging row 0..127
    const int sc = (tid & 1) * 16;      // staging col 0 or 16 (of 32)

    const float* arow = embed + (long)xidx[tile_m + sr] * 512;
    const float* brow = Wih + (long)(tile_n + sr) * 512;

    f32x4 acc[4][4];
    #pragma unroll
    for (int i = 0; i < 4; i++)
        #pragma unroll
        for (int j = 0; j < 4; j++)
            acc[i][j] = (f32x4){0.f, 0.f, 0.f, 0.f};

    for (int kc = 0; kc < 512; kc += 32) {
        __syncthreads();
        {
            const float* src = arow + kc + sc;
            unsigned short tmp[16] __attribute__((aligned(16)));
            #pragma unroll
            for (int q = 0; q < 4; q++) {
                float4 u = *(const float4*)(src + q * 4);
                tmp[q * 4 + 0] = f2bf(u.x); tmp[q * 4 + 1] = f2bf(u.y);
                tmp[q * 4 + 2] = f2bf(u.z); tmp[q * 4 + 3] = f2bf(u.w);
            }
            *(uint4*)&Asm[sr * 40 + sc]     = *(const uint4*)tmp;
            *(uint4*)&Asm[sr * 40 + sc + 8] = *(const uint4*)(tmp + 8);
        }
        {
            const float* src = brow + kc + sc;
            unsigned short tmp[16] __attribute__((aligned(16)));
            #pragma unroll
            for (int q = 0; q < 4; q++) {
                float4 u = *(const float4*)(src + q * 4);
                tmp[q * 4 + 0] = f2bf(u.x); tmp[q * 4 + 1] = f2bf(u.y);
                tmp[q * 4 + 2] = f2bf(u.z); tmp[q * 4 + 3] = f2bf(u.w);
            }
            *(uint4*)&Bsm[sr * 40 + sc]     = *(const uint4*)tmp;
            *(uint4*)&Bsm[sr * 40 + sc + 8] = *(const uint4*)(tmp + 8);
        }
        __syncthreads();
        bf16x8 af[4], bf[4];
        #pragma unroll
        for (int mi = 0; mi < 4; mi++)
            af[mi] = *(const bf16x8*)&Asm[(wm + mi * 16 + fr) * 40 + fq];
        #pragma unroll
        for (int ni = 0; ni < 4; ni++)
            bf[ni] = *(const bf16x8*)&Bsm[(wn + ni * 16 + fr) * 40 + fq];
        #pragma unroll
        for (int mi = 0; mi < 4; mi++)
            #pragma unroll
            for (int ni = 0; ni < 4; ni++)
                acc[mi][ni] = __builtin_amdgcn_mfma_f32_16x16x32_bf16(
                    af[mi], bf[ni], acc[mi][ni], 0, 0, 0);
    }

    // C/D layout: col = lane&15, row = (lane>>4)*4 + rg
    #pragma unroll
    for (int mi = 0; mi < 4; mi++) {
        #pragma unroll
        for (int ni = 0; ni < 4; ni++) {
            #pragma unroll
            for (int rg = 0; rg < 4; rg++) {
                int row = tile_m + wm + mi * 16 + (lane >> 4) * 4 + rg;
                int col = tile_n + wn + ni * 16 + (lane & 15);
                float v = acc[mi][ni][rg] + bias[col];
                Zx[(long)row * 2048 + col] = f2bf(v);
            }
        }
    }
}

// ---------------------------------------------------------------------------
// Persistent LSTM recurrence, 64 blocks x 512 threads (8 waves).
// bg = blockIdx>>4 owns batches [bg*16,+16); nb = blockIdx&15 owns cols
// [nb*32,+32) of every gate (128 W_hh rows in registers: 16 bf16x8/lane).
// Fence-free sentinel sync on Hs (0xFFFFFFFF = bf16 NaN pair, unreachable).
// R9: incremental staging (store-on-arrival, busy re-poll of pending only),
// own-chunk bypass (gate threads seed next-step hsm directly; poll 15/16),
// 4 independent MFMA accumulators.
// ---------------------------------------------------------------------------
#define WSTRIDE 520
#define SENT 0xFFFFFFFFu
#define ZL(g,r,d) zl[((g)*16+(r))*33+(d)]

__global__ __launch_bounds__(512)
void persistent_lstm(const float* __restrict__ Whh,         // f32 [2048][512]
                     const unsigned short* __restrict__ Zx, // bf16 [16384][2048]
                     unsigned int* __restrict__ Hsu)        // Hs as dwords
{
    __shared__ __align__(16) unsigned short hsm[16 * WSTRIDE];  // 16,640 B
    __shared__ float zl[4 * 16 * 33];                           //  8,448 B

    const int bg = blockIdx.x >> 4;
    const int nb = blockIdx.x & 15;
    const int tid = threadIdx.x;
    const int w = tid >> 6;        // 0..7
    const int lane = tid & 63;
    const int fr = lane & 15;
    const int fq = (lane >> 4) * 8;
    const int g = w >> 1;          // gate
    const int f = w & 1;           // 16-row fragment within gate's 32 cols

    // ---- one-time: this wave's W_hh fragment rows into registers ----
    bf16x8 wfrag[16];
    {
        const float* wrow = Whh + (long)(g * 512 + nb * 32 + f * 16 + fr) * 512;
        #pragma unroll
        for (int c = 0; c < 16; c++) {
            int k0 = c * 32 + fq;
            float4 u0 = *(const float4*)(wrow + k0);
            float4 u1 = *(const float4*)(wrow + k0 + 4);
            unsigned short tmp[8] __attribute__((aligned(16)));
            tmp[0] = f2bf(u0.x); tmp[1] = f2bf(u0.y); tmp[2] = f2bf(u0.z); tmp[3] = f2bf(u0.w);
            tmp[4] = f2bf(u1.x); tmp[5] = f2bf(u1.y); tmp[6] = f2bf(u1.z); tmp[7] = f2bf(u1.w);
            wfrag[c] = *(const bf16x8*)tmp;
        }
    }

    // staging ownership: dp = tid&255 (same col-pair for all 8 rows),
    // rows r = it*2 + (tid>>8). Own chunk (dp>>4 == nb) is seeded by gate
    // threads -> skip polling it.
    const int dp = tid & 255;
    const int rbase = tid >> 8;
    const bool skip_own = ((dp >> 4) == nb);

    // gate-math ownership (threads 0..255): row grow, col pair (d0, d0+1)
    const int grow = (tid & 255) >> 4;
    const int d0 = (tid & 15) * 2;
    const int b_own = bg * 16 + grow;
    const int dg = nb * 32 + d0;
    float ca = 0.f, cb = 0.f;      // cell state in registers (threads < 256)

    f32x4 zero4 = {0.f, 0.f, 0.f, 0.f};

    for (int t = 0; t < T_; t++) {
        // Zx gate pre-activations: independent of h -> issue early
        unsigned zi_u = 0, zf_u = 0, zg_u = 0, zo_u = 0;
        if (tid < 256) {
            const long zb = ((long)b_own * T_ + t) * H4 + dg;
            zi_u = *(const unsigned*)&Zx[zb + 0 * 512];
            zf_u = *(const unsigned*)&Zx[zb + 1 * 512];
            zg_u = *(const unsigned*)&Zx[zb + 2 * 512];
            zo_u = *(const unsigned*)&Zx[zb + 3 * 512];
        }

        f32x4 acc = zero4;
        if (t > 0) {
            // poll-stage peer chunks of h_{t-1}; store to LDS on arrival
            long ad[8];
            unsigned pend = skip_own ? 0u : 0xFFu;
            if (!skip_own) {
                #pragma unroll
                for (int it = 0; it < 8; it++) {
                    ad[it] = ((long)(bg * 16 + it * 2 + rbase) * T_ + (t - 1)) * 256 + dp;
                }
            }
            while (true) {
                if (pend) {
                    #pragma unroll
                    for (int it = 0; it < 8; it++) {
                        if (pend & (1u << it)) {
                            unsigned v = __hip_atomic_load(Hsu + ad[it], __ATOMIC_RELAXED,
                                                           __HIP_MEMORY_SCOPE_AGENT);
                            if (v != SENT) {
                                *(unsigned*)&hsm[(it * 2 + rbase) * WSTRIDE + dp * 2] = v;
                                pend &= ~(1u << it);
                            }
                        }
                    }
                }
                if (!__ballot(pend != 0)) break;
            }
            __syncthreads();   // S1: hsm fully staged (peers + own seed)
            // z_frag = h_{t-1}[16x512] @ Wfrag^T : 16 MFMAs, 4 indep chains
            const unsigned short* arow = hsm + fr * WSTRIDE;
            f32x4 a0 = zero4, a1 = zero4, a2 = zero4, a3 = zero4;
            #pragma unroll
            for (int c = 0; c < 16; c += 4) {
                bf16x8 x0 = *(const bf16x8*)(arow + (c + 0) * 32 + fq);
                bf16x8 x1 = *(const bf16x8*)(arow + (c + 1) * 32 + fq);
                bf16x8 x2 = *(const bf16x8*)(arow + (c + 2) * 32 + fq);
                bf16x8 x3 = *(const bf16x8*)(arow + (c + 3) * 32 + fq);
                a0 = __builtin_amdgcn_mfma_f32_16x16x32_bf16(x0, wfrag[c + 0], a0, 0, 0, 0);
                a1 = __builtin_amdgcn_mfma_f32_16x16x32_bf16(x1, wfrag[c + 1], a1, 0, 0, 0);
                a2 = __builtin_amdgcn_mfma_f32_16x16x32_bf16(x2, wfrag[c + 2], a2, 0, 0, 0);
                a3 = __builtin_amdgcn_mfma_f32_16x16x32_bf16(x3, wfrag[c + 3], a3, 0, 0, 0);
            }
            acc = (a0 + a1) + (a2 + a3);
        }
        // scatter z to LDS (C/D: col=lane&15, row=(lane>>4)*4+reg)
        {
            const int q4 = (lane >> 4) * 4;
            const int cl = f * 16 + (lane & 15);
            #pragma unroll
            for (int rg = 0; rg < 4; rg++) {
                ZL(g, q4 + rg, cl) = acc[rg];
            }
        }
        __syncthreads();       // S2: zl complete; hsm reads done
        // gate math on threads 0..255 (wave-uniform branch)
        if (tid < 256) {
            float zi0 = ZL(0, grow, d0)     + bf2f_lo(zi_u);
            float zi1 = ZL(0, grow, d0 + 1) + bf2f_hi(zi_u);
            float zf0 = ZL(1, grow, d0)     + bf2f_lo(zf_u);
            float zf1 = ZL(1, grow, d0 + 1) + bf2f_hi(zf_u);
            float zg0 = ZL(2, grow, d0)     + bf2f_lo(zg_u);
            float zg1 = ZL(2, grow, d0 + 1) + bf2f_hi(zg_u);
            float zo0 = ZL(3, grow, d0)     + bf2f_lo(zo_u);
            float zo1 = ZL(3, grow, d0 + 1) + bf2f_hi(zo_u);

            ca = sigmoidf_(zf0) * ca + sigmoidf_(zi0) * tanhf(zg0);
            cb = sigmoidf_(zf1) * cb + sigmoidf_(zi1) * tanhf(zg1);
            float h0 = sigmoidf_(zo0) * tanhf(ca);
            float h1 = sigmoidf_(zo1) * tanhf(cb);

            unsigned hp = (unsigned)f2bf(h0) | ((unsigned)f2bf(h1) << 16);
            // seed own chunk of next step's hsm (post-S2: hsm no longer read;
            // next staging writes disjoint peer addresses; S1 orders the read)
            *(unsigned*)&hsm[grow * WSTRIDE + dg] = hp;
            // publish for peers + history (relaxed agent, write-through)
            __hip_atomic_store(Hsu + ((long)b_own * T_ + t) * 256 + nb * 16 + (tid & 15),
                               hp, __ATOMIC_RELAXED, __HIP_MEMORY_SCOPE_AGENT);
        }
        // no trailing sync: S1/S2 of the next iteration provide ordering
    }
}

// ---------------------------------------------------------------------------
// Aspect normalization (unchanged)
// ---------------------------------------------------------------------------
__global__ __launch_bounds__(64)
void aspect_norm(const int* __restrict__ s,
                 const float* __restrict__ embed,
                 float* __restrict__ s_norm)
{
    __shared__ int sidx[256];
    const int tid = threadIdx.x;
    const int d = blockIdx.x * 64 + tid;
    for (int i = tid; i < 256; i += 64) sidx[i] = s[i];
    __syncthreads();
    float sum = 0.f, sq = 0.f;
    for (int i = 0; i < 256; i++) {
        float v = embed[(long)sidx[i] * D_ + d];
        sum += v; sq += v * v;
    }
    float mu = sum * (1.f / 256.f);
    float var = sq * (1.f / 256.f) - mu * mu;
    float rstd = rsqrtf(var + 1e-5f);
    for (int b = 0; b < 64; b++) {
        float acc = 0.f;
        #pragma unroll
        for (int a = 0; a < 4; a++) {
            acc += embed[(long)sidx[b * 4 + a] * D_ + d] - mu;
        }
        s_norm[b * D_ + d] = acc * rstd;
    }
}

// ---------------------------------------------------------------------------
// Softmax over T + r reduction (unchanged)
// ---------------------------------------------------------------------------
__global__ __launch_bounds__(256)
void attn_r(const float* __restrict__ apre,
            const unsigned short* __restrict__ Hs,
            float* __restrict__ r)
{
    const int b = blockIdx.y;
    const int d = blockIdx.x * 256 + threadIdx.x;
    const float* ap = apre + (long)b * T_ * D_ + d;
    const unsigned short* hp = Hs + (long)b * T_ * D_ + d;
    float mx = ap[0], sm = 1.f;
    for (int t = 1; t < T_; t++) {
        float v = ap[(long)t * D_];
        if (v > mx) { sm = sm * expf(mx - v) + 1.f; mx = v; }
        else sm += expf(v - mx);
    }
    float acc = 0.f;
    for (int t = 0; t < T_; t++) {
        acc += expf(ap[(long)t * D_] - mx) * bf2f(hp[(long)t * D_]);
    }
    r[b * D_ + d] = acc / sm;
}

// ---------------------------------------------------------------------------
// h_star = tanh(r @ w_p^T + Hs[:, -1] @ w_x^T) (unchanged)
// ---------------------------------------------------------------------------
__global__ __launch_bounds__(256)
void hstar_kernel(const float* __restrict__ r,
                  const unsigned short* __restrict__ Hs,
                  const float* __restrict__ w_p,
                  const float* __restrict__ w_x,
                  float* __restrict__ h_star)
{
    __shared__ float rs[512];
    __shared__ float hts[512];
    const int b = blockIdx.x, tid = threadIdx.x;
    const long hlast = ((long)b * T_ + (T_ - 1)) * D_;
    rs[tid] = r[b * D_ + tid];
    rs[tid + 256] = r[b * D_ + 256 + tid];
    hts[tid] = bf2f(Hs[hlast + tid]);
    hts[tid + 256] = bf2f(Hs[hlast + 256 + tid]);
    __syncthreads();
    for (int d = tid; d < 512; d += 256) {
        const float* wp = w_p + (long)d * D_;
        const float* wx = w_x + (long)d * D_;
        float acc = 0.f;
        for (int e = 0; e < 512; e += 4) {
            float4 p1 = *(const float4*)(wp + e);
            float4 p2 = *(const float4*)(wx + e);
            acc += p1.x * rs[e] + p1.y * rs[e + 1] + p1.z * rs[e + 2] + p1.w * rs[e + 3];
            acc += p2.x * hts[e] + p2.y * hts[e + 1] + p2.z * hts[e + 2] + p2.w * hts[e + 3];
        }
        h_star[b * D_ + d] = tanhf(acc);
    }
}

// ---------------------------------------------------------------------------
// out = softmax(h_star @ w_f^T + b_f) (unchanged)
// ---------------------------------------------------------------------------
__global__ __launch_bounds__(256)
void out_kernel(const float* __restrict__ h_star,
                const float* __restrict__ w_f,
                const float* __restrict__ b_f,
                float* __restrict__ out)
{
    __shared__ float hs[512];
    __shared__ float lg[512];
    __shared__ float red[8];
    const int b = blockIdx.x, tid = threadIdx.x;
    hs[tid] = h_star[b * D_ + tid];
    hs[tid + 256] = h_star[b * D_ + 256 + tid];
    __syncthreads();
    for (int d = tid; d < 512; d += 256) {
        const float* wr = w_f + (long)d * D_;
        float acc = b_f[d];
        for (int e = 0; e < 512; e += 4) {
            float4 p = *(const float4*)(wr + e);
            acc += p.x * hs[e] + p.y * hs[e + 1] + p.z * hs[e + 2] + p.w * hs[e + 3];
        }
        lg[d] = acc;
    }
    __syncthreads();
    float m0 = fmaxf(lg[tid], lg[tid + 256]);
    for (int off = 32; off > 0; off >>= 1) m0 = fmaxf(m0, __shfl_down(m0, off, 64));
    if ((tid & 63) == 0) red[tid >> 6] = m0;
    __syncthreads();
    float bmax = fmaxf(fmaxf(red[0], red[1]), fmaxf(red[2], red[3]));
    float e0 = expf(lg[tid] - bmax);
    float e1 = expf(lg[tid + 256] - bmax);
    float s0 = e0 + e1;
    for (int off = 32; off > 0; off >>= 1) s0 += __shfl_down(s0, off, 64);
    if ((tid & 63) == 0) red[4 + (tid >> 6)] = s0;
    __syncthreads();
    float inv = 1.f / (red[4] + red[5] + red[6] + red[7]);
    out[b * D_ + tid] = e0 * inv;
    out[b * D_ + 256 + tid] = e1 * inv;
}

// ---------------------------------------------------------------------------
extern "C" void kernel_launch(void* const* d_in, const int* in_sizes, int n_in,
                              void* d_out, int out_size, void* d_ws, size_t ws_size,
                              hipStream_t stream)
{
    (void)in_sizes; (void)n_in; (void)out_size; (void)ws_size;

    const int* x = (const int*)d_in[0];
    const int* s = (const int*)d_in[1];
    const float* embed  = (const float*)d_in[2];
    const float* W_ih   = (const float*)d_in[3];
    const float* W_hh   = (const float*)d_in[4];
    const float* b_lstm = (const float*)d_in[5];
    const float* w_y = (const float*)d_in[6];
    const float* w_t = (const float*)d_in[7];
    const float* w_p = (const float*)d_in[8];
    const float* w_x = (const float*)d_in[9];
    const float* w_f = (const float*)d_in[10];
    const float* b_f = (const float*)d_in[11];

    // Workspace (overlaid), peak ~86.5 MB:
    //   [0,64MiB)   phase1: Zx bf16 [16384][2048]
    //               phase2: apre f32 @0, mbuf bf16 @32MiB, Ybuf bf16 @48MiB
    //   [64MiB,+16MiB) Hs bf16 (doubles as the h exchange; sentinel-filled)
    //   @86114304: s_norm, @86245376: rbuf, @86376448: hstar
    char* ws = (char*)d_ws;
    unsigned short* Zx   = (unsigned short*)(ws + 0);
    float*          apre = (float*)(ws + 0);
    unsigned short* mbuf = (unsigned short*)(ws + 33554432);
    unsigned short* Ybuf = (unsigned short*)(ws + 50331648);
    unsigned short* Hs   = (unsigned short*)(ws + 67108864);
    float* s_norm = (float*)(ws + 86114304);
    float* rbuf   = (float*)(ws + 86245376);
    float* hstar  = (float*)(ws + 86376448);

    // 0) sentinel-fill Hs (0xFF bytes -> 0xFFFFFFFF dwords = bf16 NaN pairs)
    hipMemsetAsync(Hs, 0xFF, (size_t)B_ * T_ * D_ * 2, stream);

    // 1) aspect normalization
    aspect_norm<<<dim3(8), dim3(64), 0, stream>>>(s, embed, s_norm);

    // 2) G1: Zx = embed[x] @ W_ih^T + b_lstm  (128x128 tiles)
    gemm128_g1<<<dim3(16, 128), dim3(256), 0, stream>>>(
        embed, x, W_ih, b_lstm, Zx);

    // 3) recurrence: ONE persistent kernel, 64 blocks x 512 threads
    persistent_lstm<<<dim3(64), dim3(512), 0, stream>>>(
        W_hh, Zx, (unsigned int*)Hs);

    // ---- phase 2: Zx dead; region reused for apre/mbuf/Ybuf ----

    // 4) G2: m[b] = Hs[b] @ circ(s_norm[b])^T
    gemm_bt<<<dim3(8, 4, 64), dim3(256), 0, stream>>>(
        Hs, 0, nullptr, nullptr, s_norm, nullptr, mbuf, nullptr,
        512, 512, (long)(T_ * D_), (long)(T_ * D_), 0);

    // 5) G3: Y = tanh(m @ w_y^T)
    gemm_bt<<<dim3(8, 256, 1), dim3(256), 0, stream>>>(
        mbuf, 0, nullptr, w_y, nullptr, nullptr, Ybuf, nullptr,
        512, 512, 0L, 0L, 1);

    // 6) G4: apre = Y @ w_t^T
    gemm_bt<<<dim3(8, 256, 1), dim3(256), 0, stream>>>(
        Ybuf, 0, nullptr, w_t, nullptr, nullptr, nullptr, apre,
        512, 512, 0L, 0L, 0);

    // 7) softmax over T + r reduction
    attn_r<<<dim3(2, 64), dim3(256), 0, stream>>>(apre, Hs, rbuf);

    // 8) h_star
    hstar_kernel<<<dim3(64), dim3(256), 0, stream>>>(rbuf, Hs, w_p, w_x, hstar);

    // 9) final logits + softmax
    out_kernel<<<dim3(64), dim3(256), 0, stream>>>(hstar, w_f, b_f, (float*)d_out);
}